// Round 5
// baseline (354.422 us; speedup 1.0000x reference)
//
#include <hip/hip_runtime.h>

// Problem constants (fixed by reference setup_inputs)
#define BT    16384          // b*t = 4*4096
#define TSEQ  4096           // time steps per batch
#define DM    1024           // d_model
#define EXP   1024           // expanded
#define N1    2048           // 2*EXP
#define KDIM  1024           // GEMM K (both GEMMs)
#define NKT   (KDIM / 64)    // 16 K-tiles
#define EPSV  1e-8f

typedef __bf16 bf16x8 __attribute__((ext_vector_type(8)));
typedef float f32x16 __attribute__((ext_vector_type(16)));
typedef unsigned short u16x8 __attribute__((ext_vector_type(8)));

#define AS1CAST(p) ((__attribute__((address_space(1))) void*)(p))
#define AS3CAST(p) ((__attribute__((address_space(3))) void*)(p))

__device__ __forceinline__ unsigned short f2bf(float f) {
    unsigned int u = __float_as_uint(f);
    u += 0x7fffu + ((u >> 16) & 1u);
    return (unsigned short)(u >> 16);
}

// ---------------------------------------------------------------------------
// fp32 -> bf16 conversion for all three inputs in ONE launch (4 elems/thread).
__global__ __launch_bounds__(256) void k_f2bf3(const float* __restrict__ i0, unsigned short* __restrict__ o0, int n0,
                                               const float* __restrict__ i1, unsigned short* __restrict__ o1, int n1,
                                               const float* __restrict__ i2, unsigned short* __restrict__ o2, int n2) {
    int i = blockIdx.x * 256 + threadIdx.x;
    const float* in; unsigned short* out;
    if (i < n0)                { in = i0; out = o0; }
    else if (i < n0 + n1)      { in = i1; out = o1; i -= n0; }
    else if (i < n0 + n1 + n2) { in = i2; out = o2; i -= n0 + n1; }
    else return;
    float4 v = ((const float4*)in)[i];
    ushort4 o;
    o.x = f2bf(v.x); o.y = f2bf(v.y); o.z = f2bf(v.z); o.w = f2bf(v.w);
    ((ushort4*)out)[i] = o;
}

// ---------------------------------------------------------------------------
// bf16 GEMM, C[m,n] = sum_k A[m,k]*B[n,k] + bias[n]
// Block tile 256(M)x128(N), 256 thr = 4 waves PARTITIONING M (wave w owns
// rows w*64..w*64+63): A fragments are wave-private, loaded global->VGPR
// double-buffered. Prefetch of A(kt+1) is issued AFTER the post-stage
// barrier so its latency overlaps compute(kt) (round-4 bug: issuing it
// before a barrier gets it drained by the barrier's vmcnt(0)).
// Only B staged through LDS (16 KB, quarter-swizzle (q+row)&7 = minimal
// bank pattern). Wave tile 64x128 = 2x4 grid of 32x32x16 MFMA (128 AGPR).
// Epilogue: per-row sumsq (shuffle + atomicAdd) for downstream RMSNorm.
template <int BF16_OUT>
__device__ __forceinline__ void gemm_body(const unsigned short* __restrict__ A,
                                          const unsigned short* __restrict__ Bw,
                                          const float* __restrict__ bias,
                                          unsigned short* __restrict__ Cb,
                                          float* __restrict__ Cf,
                                          float* __restrict__ ssq,
                                          int N) {
    __shared__ unsigned short sB[128 * 64];   // 16 KB

    const int tid  = threadIdx.x;
    const int lane = tid & 63;
    const int w    = tid >> 6;
    const int ln   = lane & 31;
    const int hi   = lane >> 5;
    const int row0 = blockIdx.y * 256, col0 = blockIdx.x * 128;

    // A direct: wave-private rows w*64 + {0,32} + ln; lane reads 16B at
    // k = kt*64 + ks*16 + hi*8.
    const unsigned short* aRow0 = A + (size_t)(row0 + w * 64 + ln) * KDIM + hi * 8;
    const unsigned short* aRow1 = aRow0 + (size_t)32 * KDIM;

    // B staging: 1024 slots of 16B; thread covers slots s = b*256 + tid.
    // row r = s>>3 = b*32 + (tid>>3); logical quarter q = ((tid&7)-r)&7,
    // b-independent since b*32 == 0 (mod 8).
    const int r_b = tid >> 3;
    const int q_b = ((tid & 7) - r_b) & 7;
    const unsigned short* bSrc = Bw + (size_t)(col0 + r_b) * KDIM + q_b * 8;

    f32x16 acc[2][4] = {};

    auto loadA = [&](bf16x8* ar, int kt) {
#pragma unroll
        for (int ks = 0; ks < 4; ++ks) {
            ar[ks]     = *(const bf16x8*)(aRow0 + kt * 64 + ks * 16);
            ar[4 + ks] = *(const bf16x8*)(aRow1 + kt * 64 + ks * 16);
        }
    };
    auto stageB = [&](int kt) {
#pragma unroll
        for (int b = 0; b < 4; ++b)
            __builtin_amdgcn_global_load_lds(AS1CAST(bSrc + (size_t)b * 32 * KDIM + kt * 64),
                                             AS3CAST(&sB[(b * 256 + w * 64) * 8]), 16, 0, 0);
    };
    auto compute = [&](const bf16x8* ar) {
#pragma unroll
        for (int ks = 0; ks < 4; ++ks) {
            const int sw = ((ks * 2 + hi + ln) & 7) * 8;   // swizzled quarter
            bf16x8 bF[4];
#pragma unroll
            for (int j = 0; j < 4; ++j)
                bF[j] = *(const bf16x8*)&sB[(j * 32 + ln) * 64 + sw];
#pragma unroll
            for (int i = 0; i < 2; ++i)
#pragma unroll
                for (int j = 0; j < 4; ++j)
                    acc[i][j] = __builtin_amdgcn_mfma_f32_32x32x16_bf16(
                        ar[i * 4 + ks], bF[j], acc[i][j], 0, 0, 0);
        }
    };

    bf16x8 a0[8], a1[8];
    loadA(a0, 0);
    for (int kt = 0; kt < NKT; kt += 2) {
        __syncthreads();                  // consumers of sB(kt-1) done
        stageB(kt);
        __syncthreads();                  // sB(kt) ready (drains stage)
        loadA(a1, kt + 1);                // in flight across compute(a0)
        compute(a0);
        __syncthreads();
        stageB(kt + 1);
        __syncthreads();
        loadA(a0, (kt + 2 < NKT) ? kt + 2 : 0);   // last one harmless
        compute(a1);
    }

    // epilogue — C/D: col = lane&31 (+j*32), row = (reg&3) + 8*(reg>>2) + 4*hi
    const int c0 = col0 + ln;
    float bs[4];
#pragma unroll
    for (int j = 0; j < 4; ++j) bs[j] = bias[c0 + j * 32];

#pragma unroll
    for (int i = 0; i < 2; ++i) {
        const int rb = row0 + w * 64 + i * 32 + 4 * hi;
#pragma unroll
        for (int reg = 0; reg < 16; ++reg) {
            const int gm = rb + (reg & 3) + 8 * (reg >> 2);
            float v[4]; float p = 0.f;
#pragma unroll
            for (int j = 0; j < 4; ++j) {
                v[j] = acc[i][j][reg] + bs[j];
                p += v[j] * v[j];
            }
#pragma unroll
            for (int off = 1; off < 32; off <<= 1) p += __shfl_xor(p, off, 64);
            if (ln == 0) atomicAdd(&ssq[gm], p);
            size_t base = (size_t)gm * N + c0;
#pragma unroll
            for (int j = 0; j < 4; ++j) {
                if (BF16_OUT) Cb[base + j * 32] = f2bf(v[j]);
                else          Cf[base + j * 32] = v[j];
            }
        }
    }
}

__global__ __launch_bounds__(256, 2) void k_gemm_in(const unsigned short* __restrict__ A,
                                                    const unsigned short* __restrict__ Bw,
                                                    const float* __restrict__ bias,
                                                    unsigned short* __restrict__ Cb,
                                                    float* __restrict__ ssq) {
    gemm_body<1>(A, Bw, bias, Cb, nullptr, ssq, N1);
}

__global__ __launch_bounds__(256, 2) void k_gemm_out(const unsigned short* __restrict__ A,
                                                     const unsigned short* __restrict__ Bw,
                                                     const float* __restrict__ bias,
                                                     float* __restrict__ Cf,
                                                     float* __restrict__ ssq) {
    gemm_body<0>(A, Bw, bias, nullptr, Cf, ssq, DM);
}

// ---------------------------------------------------------------------------
// RMSNorm(z) -> split x|v -> depthwise conv(K=3, same, per-batch) -> gate
// 2 tokens / block; 128 threads/token; 8 channels/thread.
__global__ __launch_bounds__(256) void k_conv_gate(const unsigned short* __restrict__ z,
                                                   const float* __restrict__ ssq1,
                                                   const float* __restrict__ inw,
                                                   const float* __restrict__ cw,
                                                   const float* __restrict__ cb,
                                                   unsigned short* __restrict__ g) {
    const int tok = blockIdx.x * 2 + (threadIdx.x >> 7);
    const int e8  = (threadIdx.x & 127) * 8;
    const int t   = tok & (TSEQ - 1);

    const float rs0 = rsqrtf(ssq1[tok] * (1.0f / N1) + EPSV);
    const int tm = (t > 0) ? tok - 1 : tok;
    const int tp = (t < TSEQ - 1) ? tok + 1 : tok;
    const float rsm = (t > 0) ? rsqrtf(ssq1[tm] * (1.0f / N1) + EPSV) : 0.0f;
    const float rsp = (t < TSEQ - 1) ? rsqrtf(ssq1[tp] * (1.0f / N1) + EPSV) : 0.0f;

    bf16x8 xm = *(const bf16x8*)(z + (size_t)tm * N1 + e8);
    bf16x8 x0 = *(const bf16x8*)(z + (size_t)tok * N1 + e8);
    bf16x8 xp = *(const bf16x8*)(z + (size_t)tp * N1 + e8);
    bf16x8 vv = *(const bf16x8*)(z + (size_t)tok * N1 + EXP + e8);

    u16x8 ov;
#pragma unroll
    for (int p = 0; p < 8; ++p) {
        const int e = e8 + p;
        const float we  = inw[e];
        const float wvv = inw[EXP + e];
        const float w0 = cw[e * 3], w1 = cw[e * 3 + 1], w2 = cw[e * 3 + 2];
        float y = w0 * ((float)xm[p] * rsm * we)
                + w1 * ((float)x0[p] * rs0 * we)
                + w2 * ((float)xp[p] * rsp * we)
                + cb[e];
        float vn = (float)vv[p] * rs0 * wvv;
        ov[p] = f2bf(vn * y);
    }
    *(u16x8*)(g + (size_t)tok * EXP + e8) = ov;
}

// ---------------------------------------------------------------------------
// Final RMSNorm scale in place on fp32 output: out *= rsqrt(mean)*w
__global__ __launch_bounds__(256) void k_outnorm(float* __restrict__ o,
                                                 const float* __restrict__ ssq2,
                                                 const float* __restrict__ onw) {
    const int idx = blockIdx.x * 256 + threadIdx.x;   // one float4
    const int tok = idx >> 8;                         // 256 float4 per token
    const int d4  = (idx & 255) * 4;
    const float rs = rsqrtf(ssq2[tok] * (1.0f / DM) + EPSV);
    float4 v = ((float4*)o)[idx];
    float4 w = *(const float4*)(onw + d4);
    v.x *= rs * w.x; v.y *= rs * w.y; v.z *= rs * w.z; v.w *= rs * w.w;
    ((float4*)o)[idx] = v;
}

// ---------------------------------------------------------------------------
extern "C" void kernel_launch(void* const* d_in, const int* in_sizes, int n_in,
                              void* d_out, int out_size, void* d_ws, size_t ws_size,
                              hipStream_t stream) {
    const float* u     = (const float*)d_in[0];
    const float* W_in  = (const float*)d_in[1];
    const float* b_in  = (const float*)d_in[2];
    const float* inw   = (const float*)d_in[3];
    const float* cw    = (const float*)d_in[4];
    const float* cb    = (const float*)d_in[5];
    const float* W_out = (const float*)d_in[6];
    const float* b_out = (const float*)d_in[7];
    const float* onw   = (const float*)d_in[8];
    float* out = (float*)d_out;

    char* ws = (char*)d_ws;
    unsigned short* u_bf    = (unsigned short*)ws; ws += (size_t)BT * DM * 2;     // 32 MB
    unsigned short* Win_bf  = (unsigned short*)ws; ws += (size_t)N1 * DM * 2;     //  4 MB
    unsigned short* Wout_bf = (unsigned short*)ws; ws += (size_t)DM * EXP * 2;    //  2 MB
    unsigned short* z_bf    = (unsigned short*)ws; ws += (size_t)BT * N1 * 2;     // 64 MB
    unsigned short* g_bf    = (unsigned short*)ws; ws += (size_t)BT * EXP * 2;    // 32 MB
    float* ssq1 = (float*)ws; ws += (size_t)BT * 4;
    float* ssq2 = (float*)ws; ws += (size_t)BT * 4;

    hipMemsetAsync(ssq1, 0, (size_t)BT * 2 * sizeof(float), stream);  // ssq1+ssq2 adjacent

    const int n0 = BT * DM / 4, n1c = N1 * DM / 4, n2c = DM * EXP / 4;
    k_f2bf3<<<(n0 + n1c + n2c + 255) / 256, 256, 0, stream>>>(u, u_bf, n0,
                                                              W_in, Win_bf, n1c,
                                                              W_out, Wout_bf, n2c);

    dim3 gA(N1 / 128, BT / 256);   // (16,64)
    k_gemm_in<<<gA, 256, 0, stream>>>(u_bf, Win_bf, b_in, z_bf, ssq1);

    k_conv_gate<<<BT / 2, 256, 0, stream>>>(z_bf, ssq1, inw, cw, cb, g_bf);

    dim3 gC(DM / 128, BT / 256);   // (8,64)
    k_gemm_out<<<gC, 256, 0, stream>>>(g_bf, Wout_bf, b_out, out, ssq2);

    k_outnorm<<<BT, 256, 0, stream>>>(out, ssq2, onw);

    (void)in_sizes; (void)n_in; (void)out_size; (void)ws_size;
}

// Round 6
// 309.046 us; speedup vs baseline: 1.1468x; 1.1468x over previous
//
#include <hip/hip_runtime.h>

// Problem constants (fixed by reference setup_inputs)
#define BT    16384          // b*t = 4*4096
#define TSEQ  4096           // time steps per batch
#define DM    1024           // d_model
#define EXP   1024           // expanded
#define N1    2048           // 2*EXP
#define KDIM  1024           // GEMM K (both GEMMs)
#define NKT   (KDIM / 64)    // 16 K-tiles of BK=64
#define EPSV  1e-8f

typedef __bf16 bf16x8 __attribute__((ext_vector_type(8)));
typedef float f32x16 __attribute__((ext_vector_type(16)));
typedef unsigned short u16x8 __attribute__((ext_vector_type(8)));

#define AS1CAST(p) ((__attribute__((address_space(1))) void*)(p))
#define AS3CAST(p) ((__attribute__((address_space(3))) void*)(p))

__device__ __forceinline__ unsigned short f2bf(float f) {
    unsigned int u = __float_as_uint(f);
    u += 0x7fffu + ((u >> 16) & 1u);
    return (unsigned short)(u >> 16);
}

// ---------------------------------------------------------------------------
// fp32 -> bf16 conversion for all three inputs + zero-init of ssq[2*BT],
// all in ONE launch (4 elems/thread).
__global__ __launch_bounds__(256) void k_f2bf3(const float* __restrict__ i0, unsigned short* __restrict__ o0, int n0,
                                               const float* __restrict__ i1, unsigned short* __restrict__ o1, int n1,
                                               const float* __restrict__ i2, unsigned short* __restrict__ o2, int n2,
                                               float* __restrict__ ssq) {
    int i = blockIdx.x * 256 + threadIdx.x;
    const float* in; unsigned short* out;
    if (i < n0)                { in = i0; out = o0; }
    else if (i < n0 + n1)      { in = i1; out = o1; i -= n0; }
    else if (i < n0 + n1 + n2) { in = i2; out = o2; i -= n0 + n1; }
    else {
        i -= n0 + n1 + n2;
        if (i < 2 * BT / 4) ((float4*)ssq)[i] = make_float4(0.f, 0.f, 0.f, 0.f);
        return;
    }
    float4 v = ((const float4*)in)[i];
    ushort4 o;
    o.x = f2bf(v.x); o.y = f2bf(v.y); o.z = f2bf(v.z); o.w = f2bf(v.w);
    ((ushort4*)out)[i] = o;
}

// ---------------------------------------------------------------------------
// bf16 GEMM, C[m,n] = sum_k A[m,k]*B[n,k] + bias[n]
// Block tile 256(M)x128(N), 256 thr = 4 waves partitioning M; wave tile
// 64x128 = 2x4 grid of 32x32x16 MFMA (128 AGPR). Both A and B staged in
// LDS (A 32KB + B 16KB), quarter-swizzled (q+row)&7 so operand ds_reads
// hit the minimal 8-access bank pattern (round-3 verified). Per kt a wave
// issues 24 ds_read_b128 for 32 MFMA (vs 16:16 at 128x128 — 25% less LDS
// read traffic per FLOP).
// Grid is 1-D with an XCD swizzle: blocks sharing an A-tile (same mt) are
// spaced 8 apart in linear ID so round-robin dispatch puts them on ONE
// XCD -> A fetched once per XCD (round-3/5 FETCH_SIZE showed ~4x A refetch).
// Epilogue: per-row sumsq (shuffle + atomicAdd) for downstream RMSNorm.
template <int BF16_OUT, int NT>
__device__ __forceinline__ void gemm_body(const unsigned short* __restrict__ A,
                                          const unsigned short* __restrict__ Bw,
                                          const float* __restrict__ bias,
                                          unsigned short* __restrict__ Cb,
                                          float* __restrict__ Cf,
                                          float* __restrict__ ssq,
                                          int N) {
    __shared__ unsigned short sA[256 * 64];   // 32 KB
    __shared__ unsigned short sB[128 * 64];   // 16 KB

    const int tid  = threadIdx.x;
    const int lane = tid & 63;
    const int w    = tid >> 6;
    const int ln   = lane & 31;
    const int hi   = lane >> 5;

    // XCD swizzle: lane-in-8 picks mt within a super-row of 8 M-tiles.
    const int L   = blockIdx.x;
    const int mt  = ((L >> 3) / NT) * 8 + (L & 7);
    const int nt  = (L >> 3) & (NT - 1);
    const int row0 = mt * 256, col0 = nt * 128;

    // Staging (16B slots, quarter-swizzled): slot s = b*256 + tid covers
    // row r = s>>3, logical quarter q = ((tid&7) - r) & 7 (b-independent
    // since b*32 == 0 mod 8).
    const int rA = tid >> 3;                       // r = b*32 + rA
    const int qS = ((tid & 7) - rA) & 7;
    const unsigned short* aSrc = A  + (size_t)(row0 + rA) * KDIM + qS * 8;
    const unsigned short* bSrc = Bw + (size_t)(col0 + rA) * KDIM + qS * 8;

    f32x16 acc[2][4] = {};

    for (int kt = 0; kt < NKT; ++kt) {
        __syncthreads();
#pragma unroll
        for (int b = 0; b < 8; ++b)
            __builtin_amdgcn_global_load_lds(AS1CAST(aSrc + (size_t)b * 32 * KDIM + kt * 64),
                                             AS3CAST(&sA[(b * 256 + w * 64) * 8]), 16, 0, 0);
#pragma unroll
        for (int b = 0; b < 4; ++b)
            __builtin_amdgcn_global_load_lds(AS1CAST(bSrc + (size_t)b * 32 * KDIM + kt * 64),
                                             AS3CAST(&sB[(b * 256 + w * 64) * 8]), 16, 0, 0);
        __syncthreads();

#pragma unroll
        for (int ks = 0; ks < 4; ++ks) {
            const int sw = ((ks * 2 + hi + ln) & 7) * 8;   // swizzled quarter
            bf16x8 aF[2], bF[4];
#pragma unroll
            for (int i = 0; i < 2; ++i)
                aF[i] = *(const bf16x8*)&sA[(w * 64 + i * 32 + ln) * 64 + sw];
#pragma unroll
            for (int j = 0; j < 4; ++j)
                bF[j] = *(const bf16x8*)&sB[(j * 32 + ln) * 64 + sw];
#pragma unroll
            for (int i = 0; i < 2; ++i)
#pragma unroll
                for (int j = 0; j < 4; ++j)
                    acc[i][j] = __builtin_amdgcn_mfma_f32_32x32x16_bf16(
                        aF[i], bF[j], acc[i][j], 0, 0, 0);
        }
    }

    // epilogue — C/D: col = lane&31 (+j*32), row = (reg&3) + 8*(reg>>2) + 4*hi
    const int c0 = col0 + ln;
    float bs[4];
#pragma unroll
    for (int j = 0; j < 4; ++j) bs[j] = bias[c0 + j * 32];

#pragma unroll
    for (int i = 0; i < 2; ++i) {
        const int rb = row0 + w * 64 + i * 32 + 4 * hi;
#pragma unroll
        for (int reg = 0; reg < 16; ++reg) {
            const int gm = rb + (reg & 3) + 8 * (reg >> 2);
            float v[4]; float p = 0.f;
#pragma unroll
            for (int j = 0; j < 4; ++j) {
                v[j] = acc[i][j][reg] + bs[j];
                p += v[j] * v[j];
            }
#pragma unroll
            for (int off = 1; off < 32; off <<= 1) p += __shfl_xor(p, off, 64);
            if (ln == 0) atomicAdd(&ssq[gm], p);
            size_t base = (size_t)gm * N + c0;
#pragma unroll
            for (int j = 0; j < 4; ++j) {
                if (BF16_OUT) Cb[base + j * 32] = f2bf(v[j]);
                else          Cf[base + j * 32] = v[j];
            }
        }
    }
}

__global__ __launch_bounds__(256, 2) void k_gemm_in(const unsigned short* __restrict__ A,
                                                    const unsigned short* __restrict__ Bw,
                                                    const float* __restrict__ bias,
                                                    unsigned short* __restrict__ Cb,
                                                    float* __restrict__ ssq) {
    gemm_body<1, 16>(A, Bw, bias, Cb, nullptr, ssq, N1);
}

__global__ __launch_bounds__(256, 2) void k_gemm_out(const unsigned short* __restrict__ A,
                                                     const unsigned short* __restrict__ Bw,
                                                     const float* __restrict__ bias,
                                                     float* __restrict__ Cf,
                                                     float* __restrict__ ssq) {
    gemm_body<0, 8>(A, Bw, bias, nullptr, Cf, ssq, DM);
}

// ---------------------------------------------------------------------------
// RMSNorm(z) -> split x|v -> depthwise conv(K=3, same, per-batch) -> gate
// 2 tokens / block; 128 threads/token; 8 channels/thread.
__global__ __launch_bounds__(256) void k_conv_gate(const unsigned short* __restrict__ z,
                                                   const float* __restrict__ ssq1,
                                                   const float* __restrict__ inw,
                                                   const float* __restrict__ cw,
                                                   const float* __restrict__ cb,
                                                   unsigned short* __restrict__ g) {
    const int tok = blockIdx.x * 2 + (threadIdx.x >> 7);
    const int e8  = (threadIdx.x & 127) * 8;
    const int t   = tok & (TSEQ - 1);

    const float rs0 = rsqrtf(ssq1[tok] * (1.0f / N1) + EPSV);
    const int tm = (t > 0) ? tok - 1 : tok;
    const int tp = (t < TSEQ - 1) ? tok + 1 : tok;
    const float rsm = (t > 0) ? rsqrtf(ssq1[tm] * (1.0f / N1) + EPSV) : 0.0f;
    const float rsp = (t < TSEQ - 1) ? rsqrtf(ssq1[tp] * (1.0f / N1) + EPSV) : 0.0f;

    bf16x8 xm = *(const bf16x8*)(z + (size_t)tm * N1 + e8);
    bf16x8 x0 = *(const bf16x8*)(z + (size_t)tok * N1 + e8);
    bf16x8 xp = *(const bf16x8*)(z + (size_t)tp * N1 + e8);
    bf16x8 vv = *(const bf16x8*)(z + (size_t)tok * N1 + EXP + e8);

    u16x8 ov;
#pragma unroll
    for (int p = 0; p < 8; ++p) {
        const int e = e8 + p;
        const float we  = inw[e];
        const float wvv = inw[EXP + e];
        const float w0 = cw[e * 3], w1 = cw[e * 3 + 1], w2 = cw[e * 3 + 2];
        float y = w0 * ((float)xm[p] * rsm * we)
                + w1 * ((float)x0[p] * rs0 * we)
                + w2 * ((float)xp[p] * rsp * we)
                + cb[e];
        float vn = (float)vv[p] * rs0 * wvv;
        ov[p] = f2bf(vn * y);
    }
    *(u16x8*)(g + (size_t)tok * EXP + e8) = ov;
}

// ---------------------------------------------------------------------------
// Final RMSNorm scale in place on fp32 output: out *= rsqrt(mean)*w
__global__ __launch_bounds__(256) void k_outnorm(float* __restrict__ o,
                                                 const float* __restrict__ ssq2,
                                                 const float* __restrict__ onw) {
    const int idx = blockIdx.x * 256 + threadIdx.x;   // one float4
    const int tok = idx >> 8;                         // 256 float4 per token
    const int d4  = (idx & 255) * 4;
    const float rs = rsqrtf(ssq2[tok] * (1.0f / DM) + EPSV);
    float4 v = ((float4*)o)[idx];
    float4 w = *(const float4*)(onw + d4);
    v.x *= rs * w.x; v.y *= rs * w.y; v.z *= rs * w.z; v.w *= rs * w.w;
    ((float4*)o)[idx] = v;
}

// ---------------------------------------------------------------------------
extern "C" void kernel_launch(void* const* d_in, const int* in_sizes, int n_in,
                              void* d_out, int out_size, void* d_ws, size_t ws_size,
                              hipStream_t stream) {
    const float* u     = (const float*)d_in[0];
    const float* W_in  = (const float*)d_in[1];
    const float* b_in  = (const float*)d_in[2];
    const float* inw   = (const float*)d_in[3];
    const float* cw    = (const float*)d_in[4];
    const float* cb    = (const float*)d_in[5];
    const float* W_out = (const float*)d_in[6];
    const float* b_out = (const float*)d_in[7];
    const float* onw   = (const float*)d_in[8];
    float* out = (float*)d_out;

    char* ws = (char*)d_ws;
    unsigned short* u_bf    = (unsigned short*)ws; ws += (size_t)BT * DM * 2;     // 32 MB
    unsigned short* Win_bf  = (unsigned short*)ws; ws += (size_t)N1 * DM * 2;     //  4 MB
    unsigned short* Wout_bf = (unsigned short*)ws; ws += (size_t)DM * EXP * 2;    //  2 MB
    unsigned short* z_bf    = (unsigned short*)ws; ws += (size_t)BT * N1 * 2;     // 64 MB
    unsigned short* g_bf    = (unsigned short*)ws; ws += (size_t)BT * EXP * 2;    // 32 MB
    float* ssq1 = (float*)ws; ws += (size_t)BT * 4;
    float* ssq2 = (float*)ws; ws += (size_t)BT * 4;   // contiguous after ssq1

    const int n0 = BT * DM / 4, n1c = N1 * DM / 4, n2c = DM * EXP / 4;
    const int ntot = n0 + n1c + n2c + 2 * BT / 4;
    k_f2bf3<<<(ntot + 255) / 256, 256, 0, stream>>>(u, u_bf, n0,
                                                    W_in, Win_bf, n1c,
                                                    W_out, Wout_bf, n2c,
                                                    ssq1);

    k_gemm_in<<<(BT / 256) * (N1 / 128), 256, 0, stream>>>(u_bf, Win_bf, b_in, z_bf, ssq1);

    k_conv_gate<<<BT / 2, 256, 0, stream>>>(z_bf, ssq1, inw, cw, cb, g_bf);

    k_gemm_out<<<(BT / 256) * (DM / 128), 256, 0, stream>>>(g_bf, Wout_bf, b_out, out, ssq2);

    k_outnorm<<<BT, 256, 0, stream>>>(out, ssq2, onw);

    (void)in_sizes; (void)n_in; (void)out_size; (void)ws_size;
}

// Round 7
// 301.840 us; speedup vs baseline: 1.1742x; 1.0239x over previous
//
#include <hip/hip_runtime.h>

// Problem constants (fixed by reference setup_inputs)
#define BT    16384          // b*t = 4*4096
#define TSEQ  4096           // time steps per batch
#define DM    1024           // d_model
#define EXP   1024           // expanded
#define N1    2048           // 2*EXP
#define KDIM  1024           // GEMM K (both GEMMs)
#define NKT2  (KDIM / 32)    // 32 K-tiles of BK=32 (double-buffered)
#define EPSV  1e-8f

typedef __bf16 bf16x8 __attribute__((ext_vector_type(8)));
typedef float f32x16 __attribute__((ext_vector_type(16)));
typedef unsigned short u16x8 __attribute__((ext_vector_type(8)));

#define AS1CAST(p) ((__attribute__((address_space(1))) void*)(p))
#define AS3CAST(p) ((__attribute__((address_space(3))) void*)(p))

__device__ __forceinline__ unsigned short f2bf(float f) {
    unsigned int u = __float_as_uint(f);
    u += 0x7fffu + ((u >> 16) & 1u);
    return (unsigned short)(u >> 16);
}

// ---------------------------------------------------------------------------
// fp32 -> bf16 conversion for all three inputs + zero-init of ssq[2*BT],
// all in ONE launch (4 elems/thread).
__global__ __launch_bounds__(256) void k_f2bf3(const float* __restrict__ i0, unsigned short* __restrict__ o0, int n0,
                                               const float* __restrict__ i1, unsigned short* __restrict__ o1, int n1,
                                               const float* __restrict__ i2, unsigned short* __restrict__ o2, int n2,
                                               float* __restrict__ ssq) {
    int i = blockIdx.x * 256 + threadIdx.x;
    const float* in; unsigned short* out;
    if (i < n0)                { in = i0; out = o0; }
    else if (i < n0 + n1)      { in = i1; out = o1; i -= n0; }
    else if (i < n0 + n1 + n2) { in = i2; out = o2; i -= n0 + n1; }
    else {
        i -= n0 + n1 + n2;
        if (i < 2 * BT / 4) ((float4*)ssq)[i] = make_float4(0.f, 0.f, 0.f, 0.f);
        return;
    }
    float4 v = ((const float4*)in)[i];
    ushort4 o;
    o.x = f2bf(v.x); o.y = f2bf(v.y); o.z = f2bf(v.z); o.w = f2bf(v.w);
    ((ushort4*)out)[i] = o;
}

// ---------------------------------------------------------------------------
// bf16 GEMM, C[m,n] = sum_k A[m,k]*B[n,k] + bias[n]
// Block tile 256(M)x128(N), 256 thr = 4 waves partitioning M; wave tile
// 64x128 = 2x4 grid of 32x32x16 MFMA (128 AGPR).
// BK=32, DOUBLE-BUFFERED LDS (A 16KB + B 8KB per buffer, 48 KB total):
// per kt: [barrier] stage(kt+1 -> other buf) compute(kt) — staging latency
// hides behind 16 MFMA + 12 ds_reads instead of being drained by a barrier
// immediately after issue (round-6 structure exposed it fully).
// Rows are 64 B = 4 sixteen-byte quarters, stored quarter-swizzled
// (q+row)&3 for the minimal bank pattern.
// XCD grid swizzle: blocks sharing an A-tile are 8 apart in linear ID ->
// same XCD under round-robin dispatch (round-6: FETCH 146->50 MB).
// Epilogue: C-store + per-lane sum-sq partials to LDS scratch [256][33],
// then one thread per row reduces 32 partials -> one atomicAdd per row.
template <int BF16_OUT, int NT>
__device__ __forceinline__ void gemm_body(const unsigned short* __restrict__ A,
                                          const unsigned short* __restrict__ Bw,
                                          const float* __restrict__ bias,
                                          unsigned short* __restrict__ Cb,
                                          float* __restrict__ Cf,
                                          float* __restrict__ ssq,
                                          int N) {
    __shared__ __align__(16) char smem[49152];
    unsigned short* sA0 = (unsigned short*)smem;              // 16 KB
    unsigned short* sB0 = (unsigned short*)(smem + 16384);    //  8 KB
    unsigned short* sA1 = (unsigned short*)(smem + 24576);    // 16 KB
    unsigned short* sB1 = (unsigned short*)(smem + 40960);    //  8 KB

    const int tid  = threadIdx.x;
    const int lane = tid & 63;
    const int w    = tid >> 6;
    const int ln   = lane & 31;
    const int hi   = lane >> 5;

    // XCD swizzle: lane-in-8 picks mt within a super-row of 8 M-tiles.
    const int L   = blockIdx.x;
    const int mt  = ((L >> 3) / NT) * 8 + (L & 7);
    const int nt  = (L >> 3) & (NT - 1);
    const int row0 = mt * 256, col0 = nt * 128;

    // Staging: 16B slots; slot s = b*256 + tid covers row r = s>>2
    // (= b*64 + (tid>>2)), phys quarter tid&3, logical quarter
    // q = ((tid&3) - r) & 3 (b-independent since b*64 == 0 mod 4).
    const int rA = tid >> 2;
    const int qS = ((tid & 3) - rA) & 3;
    const unsigned short* aSrc = A  + (size_t)(row0 + rA) * KDIM + qS * 8;
    const unsigned short* bSrc = Bw + (size_t)(col0 + rA) * KDIM + qS * 8;

    f32x16 acc[2][4] = {};

    auto stage = [&](int kt, unsigned short* sA, unsigned short* sB) {
#pragma unroll
        for (int b = 0; b < 4; ++b)
            __builtin_amdgcn_global_load_lds(AS1CAST(aSrc + (size_t)b * 64 * KDIM + kt * 32),
                                             AS3CAST(&sA[(b * 256 + w * 64) * 8]), 16, 0, 0);
#pragma unroll
        for (int b = 0; b < 2; ++b)
            __builtin_amdgcn_global_load_lds(AS1CAST(bSrc + (size_t)b * 64 * KDIM + kt * 32),
                                             AS3CAST(&sB[(b * 256 + w * 64) * 8]), 16, 0, 0);
    };
    auto compute = [&](const unsigned short* sA, const unsigned short* sB) {
#pragma unroll
        for (int ks = 0; ks < 2; ++ks) {
            const int sw = ((ks * 2 + hi + ln) & 3) * 8;   // swizzled quarter
            bf16x8 aF[2], bF[4];
#pragma unroll
            for (int i = 0; i < 2; ++i)
                aF[i] = *(const bf16x8*)&sA[(w * 64 + i * 32 + ln) * 32 + sw];
#pragma unroll
            for (int j = 0; j < 4; ++j)
                bF[j] = *(const bf16x8*)&sB[(j * 32 + ln) * 32 + sw];
#pragma unroll
            for (int i = 0; i < 2; ++i)
#pragma unroll
                for (int j = 0; j < 4; ++j)
                    acc[i][j] = __builtin_amdgcn_mfma_f32_32x32x16_bf16(
                        aF[i], bF[j], acc[i][j], 0, 0, 0);
        }
    };

    stage(0, sA0, sB0);
    for (int kt = 0; kt < NKT2; kt += 2) {
        __syncthreads();                       // stage(kt) landed; buf1 free
        stage(kt + 1, sA1, sB1);               // latency hides behind compute
        compute(sA0, sB0);
        __syncthreads();                       // stage(kt+1) landed; buf0 free
        if (kt + 2 < NKT2) stage(kt + 2, sA0, sB0);
        compute(sA1, sB1);
    }

    // ---- epilogue ----
    // C/D: col = lane&31 (+j*32), row = (reg&3) + 8*(reg>>2) + 4*hi
    const int c0 = col0 + ln;
    float bs[4];
#pragma unroll
    for (int j = 0; j < 4; ++j) bs[j] = bias[c0 + j * 32];

    __syncthreads();                           // done with LDS K-buffers
    float* scr = (float*)smem;                 // [256][33] = 33.8 KB

#pragma unroll
    for (int i = 0; i < 2; ++i) {
        const int lr0 = w * 64 + i * 32 + 4 * hi;   // local row base
#pragma unroll
        for (int reg = 0; reg < 16; ++reg) {
            const int lr = lr0 + (reg & 3) + 8 * (reg >> 2);
            const int gm = row0 + lr;
            float v[4]; float p = 0.f;
#pragma unroll
            for (int j = 0; j < 4; ++j) {
                v[j] = acc[i][j][reg] + bs[j];
                p += v[j] * v[j];
            }
            scr[lr * 33 + ln] = p;             // conflict-free: banks (lr+ln)%32
            size_t base = (size_t)gm * N + c0;
#pragma unroll
            for (int j = 0; j < 4; ++j) {
                if (BF16_OUT) Cb[base + j * 32] = f2bf(v[j]);
                else          Cf[base + j * 32] = v[j];
            }
        }
    }
    __syncthreads();
    // one thread per local row: sum its 32 partials, one atomic per row
    float s = 0.f;
#pragma unroll
    for (int c = 0; c < 32; ++c) s += scr[tid * 33 + c];
    atomicAdd(&ssq[row0 + tid], s);
}

__global__ __launch_bounds__(256, 2) void k_gemm_in(const unsigned short* __restrict__ A,
                                                    const unsigned short* __restrict__ Bw,
                                                    const float* __restrict__ bias,
                                                    unsigned short* __restrict__ Cb,
                                                    float* __restrict__ ssq) {
    gemm_body<1, 16>(A, Bw, bias, Cb, nullptr, ssq, N1);
}

__global__ __launch_bounds__(256, 2) void k_gemm_out(const unsigned short* __restrict__ A,
                                                     const unsigned short* __restrict__ Bw,
                                                     const float* __restrict__ bias,
                                                     float* __restrict__ Cf,
                                                     float* __restrict__ ssq) {
    gemm_body<0, 8>(A, Bw, bias, nullptr, Cf, ssq, DM);
}

// ---------------------------------------------------------------------------
// RMSNorm(z) -> split x|v -> depthwise conv(K=3, same, per-batch) -> gate
// 2 tokens / block; 128 threads/token; 8 channels/thread.
__global__ __launch_bounds__(256) void k_conv_gate(const unsigned short* __restrict__ z,
                                                   const float* __restrict__ ssq1,
                                                   const float* __restrict__ inw,
                                                   const float* __restrict__ cw,
                                                   const float* __restrict__ cb,
                                                   unsigned short* __restrict__ g) {
    const int tok = blockIdx.x * 2 + (threadIdx.x >> 7);
    const int e8  = (threadIdx.x & 127) * 8;
    const int t   = tok & (TSEQ - 1);

    const float rs0 = rsqrtf(ssq1[tok] * (1.0f / N1) + EPSV);
    const int tm = (t > 0) ? tok - 1 : tok;
    const int tp = (t < TSEQ - 1) ? tok + 1 : tok;
    const float rsm = (t > 0) ? rsqrtf(ssq1[tm] * (1.0f / N1) + EPSV) : 0.0f;
    const float rsp = (t < TSEQ - 1) ? rsqrtf(ssq1[tp] * (1.0f / N1) + EPSV) : 0.0f;

    bf16x8 xm = *(const bf16x8*)(z + (size_t)tm * N1 + e8);
    bf16x8 x0 = *(const bf16x8*)(z + (size_t)tok * N1 + e8);
    bf16x8 xp = *(const bf16x8*)(z + (size_t)tp * N1 + e8);
    bf16x8 vv = *(const bf16x8*)(z + (size_t)tok * N1 + EXP + e8);

    u16x8 ov;
#pragma unroll
    for (int p = 0; p < 8; ++p) {
        const int e = e8 + p;
        const float we  = inw[e];
        const float wvv = inw[EXP + e];
        const float w0 = cw[e * 3], w1 = cw[e * 3 + 1], w2 = cw[e * 3 + 2];
        float y = w0 * ((float)xm[p] * rsm * we)
                + w1 * ((float)x0[p] * rs0 * we)
                + w2 * ((float)xp[p] * rsp * we)
                + cb[e];
        float vn = (float)vv[p] * rs0 * wvv;
        ov[p] = f2bf(vn * y);
    }
    *(u16x8*)(g + (size_t)tok * EXP + e8) = ov;
}

// ---------------------------------------------------------------------------
// Final RMSNorm scale in place on fp32 output: out *= rsqrt(mean)*w
__global__ __launch_bounds__(256) void k_outnorm(float* __restrict__ o,
                                                 const float* __restrict__ ssq2,
                                                 const float* __restrict__ onw) {
    const int idx = blockIdx.x * 256 + threadIdx.x;   // one float4
    const int tok = idx >> 8;                         // 256 float4 per token
    const int d4  = (idx & 255) * 4;
    const float rs = rsqrtf(ssq2[tok] * (1.0f / DM) + EPSV);
    float4 v = ((float4*)o)[idx];
    float4 w = *(const float4*)(onw + d4);
    v.x *= rs * w.x; v.y *= rs * w.y; v.z *= rs * w.z; v.w *= rs * w.w;
    ((float4*)o)[idx] = v;
}

// ---------------------------------------------------------------------------
extern "C" void kernel_launch(void* const* d_in, const int* in_sizes, int n_in,
                              void* d_out, int out_size, void* d_ws, size_t ws_size,
                              hipStream_t stream) {
    const float* u     = (const float*)d_in[0];
    const float* W_in  = (const float*)d_in[1];
    const float* b_in  = (const float*)d_in[2];
    const float* inw   = (const float*)d_in[3];
    const float* cw    = (const float*)d_in[4];
    const float* cb    = (const float*)d_in[5];
    const float* W_out = (const float*)d_in[6];
    const float* b_out = (const float*)d_in[7];
    const float* onw   = (const float*)d_in[8];
    float* out = (float*)d_out;

    char* ws = (char*)d_ws;
    unsigned short* u_bf    = (unsigned short*)ws; ws += (size_t)BT * DM * 2;     // 32 MB
    unsigned short* Win_bf  = (unsigned short*)ws; ws += (size_t)N1 * DM * 2;     //  4 MB
    unsigned short* Wout_bf = (unsigned short*)ws; ws += (size_t)DM * EXP * 2;    //  2 MB
    unsigned short* z_bf    = (unsigned short*)ws; ws += (size_t)BT * N1 * 2;     // 64 MB
    unsigned short* g_bf    = (unsigned short*)ws; ws += (size_t)BT * EXP * 2;    // 32 MB
    float* ssq1 = (float*)ws; ws += (size_t)BT * 4;
    float* ssq2 = (float*)ws; ws += (size_t)BT * 4;   // contiguous after ssq1

    const int n0 = BT * DM / 4, n1c = N1 * DM / 4, n2c = DM * EXP / 4;
    const int ntot = n0 + n1c + n2c + 2 * BT / 4;
    k_f2bf3<<<(ntot + 255) / 256, 256, 0, stream>>>(u, u_bf, n0,
                                                    W_in, Win_bf, n1c,
                                                    W_out, Wout_bf, n2c,
                                                    ssq1);

    k_gemm_in<<<(BT / 256) * (N1 / 128), 256, 0, stream>>>(u_bf, Win_bf, b_in, z_bf, ssq1);

    k_conv_gate<<<BT / 2, 256, 0, stream>>>(z_bf, ssq1, inw, cw, cb, g_bf);

    k_gemm_out<<<(BT / 256) * (DM / 128), 256, 0, stream>>>(g_bf, Wout_bf, b_out, out, ssq2);

    k_outnorm<<<BT, 256, 0, stream>>>(out, ssq2, onw);

    (void)in_sizes; (void)n_in; (void)out_size; (void)ws_size;
}